// Round 18
// baseline (131.818 us; speedup 1.0000x reference)
//
#include <hip/hip_runtime.h>
#include <hip/hip_bf16.h>

// B=8, S=2048, H=512. out[b,i,:] = sum_{j<i} exp(q_i.x_j) x_j / (sum_{j<i} exp(q_i.x_j) + 1e-10)
// q = X @ W^T + b.
// R18: R16 base; pvgemm LDS pitch 72->68 (52.2KB -> 3 blocks/CU, the sgemm-vs-pvgemm
//      controlled delta), launch_bounds (256,3), grid (G,128) heavy-first 64-col slices.
#define BATCH 8
#define SEQ   2048
#define DIM   512

typedef __bf16 bf16x8 __attribute__((ext_vector_type(8)));
typedef float  f32x4  __attribute__((ext_vector_type(4)));

__device__ __forceinline__ ushort f2bf(float f) {
    union { float f; unsigned u; } c; c.f = f;
    unsigned u = c.u;
    u += 0x7fffu + ((u >> 16) & 1u);   // round-to-nearest-even
    return (ushort)(u >> 16);
}

// ---------------- prep: X f32 -> Xb bf16 + Xt bf16 (transposed); tail blocks do W->bf16 -------
__global__ __launch_bounds__(256) void prep_kernel(const float* __restrict__ X,
                                                   ushort* __restrict__ Xb,
                                                   ushort* __restrict__ Xt,
                                                   const float* __restrict__ W,
                                                   ushort* __restrict__ Wb) {
    __shared__ ushort T[32 * 33];
    int t   = threadIdx.x;
    int bid = blockIdx.x;              // 8192 X-blocks + 128 W-blocks
    if (bid >= 8192) {
        int gt = (bid - 8192) * 256 + t;
        size_t base = (size_t)gt * 8;
        float4 a = *(const float4*)(W + base);
        float4 c = *(const float4*)(W + base + 4);
        ushort4 lo, hi;
        lo.x = f2bf(a.x); lo.y = f2bf(a.y); lo.z = f2bf(a.z); lo.w = f2bf(a.w);
        hi.x = f2bf(c.x); hi.y = f2bf(c.y); hi.z = f2bf(c.z); hi.w = f2bf(c.w);
        *(ushort4*)(Wb + base)     = lo;
        *(ushort4*)(Wb + base + 4) = hi;
        return;
    }
    int b   = bid >> 10;
    int st  = (bid >> 4) & 63;
    int ht  = bid & 15;
    int s0 = st * 32, h0 = ht * 32;

    int r  = t >> 3;
    int c4 = (t & 7) * 4;
    size_t src = ((size_t)(b * SEQ + s0 + r)) * DIM + h0 + c4;
    float4 v = *(const float4*)(X + src);
    ushort u0 = f2bf(v.x), u1 = f2bf(v.y), u2 = f2bf(v.z), u3 = f2bf(v.w);
    ushort4 uv; uv.x = u0; uv.y = u1; uv.z = u2; uv.w = u3;
    *(ushort4*)(Xb + src) = uv;
    T[(c4 + 0) * 33 + r] = u0;
    T[(c4 + 1) * 33 + r] = u1;
    T[(c4 + 2) * 33 + r] = u2;
    T[(c4 + 3) * 33 + r] = u3;
    __syncthreads();
    int hh = t >> 3;
    int sc = (t & 7) * 4;
    ushort4 w;
    w.x = T[hh * 33 + sc + 0];
    w.y = T[hh * 33 + sc + 1];
    w.z = T[hh * 33 + sc + 2];
    w.w = T[hh * 33 + sc + 3];
    *(ushort4*)(Xt + ((size_t)(b * DIM + h0 + hh)) * SEQ + s0 + sc) = w;
}

// ---------------- qgemm: Qb = bf16(Xb @ Wb^T + bias), BK=64, depth-2 ----------------
__global__ __launch_bounds__(256, 2) void qgemm_kernel(const ushort* __restrict__ Xb,
                                                       const ushort* __restrict__ Wb,
                                                       const float* __restrict__ bias,
                                                       ushort* __restrict__ Qb) {
    __shared__ ushort At[2][128 * 72];
    __shared__ ushort Bt[2][128 * 72];
    int t   = threadIdx.x;
    int bid = blockIdx.x;              // 128 mtiles * 4 ntiles
    int mt = bid >> 2, nt = bid & 3;
    int m0 = mt << 7, n0 = nt << 7;
    int w  = t >> 6, l = t & 63, ln = l & 15, lg = l >> 4;
    int wr = w >> 1, wc = w & 1;

    f32x4 acc[4][4] = {};
    int arow = t >> 1;                 // 0..127
    int ac0  = (t & 1) * 32;           // 0 or 32

    const ushort* Arow = Xb + (size_t)m0 * 512;
    const ushort* Brow = Wb + (size_t)n0 * 512;

#define QG_LOAD(KS, A0, A1, A2, A3, B0, B1, B2, B3)                                \
    {                                                                              \
        const ushort* pa_ = Arow + (size_t)arow * 512 + (KS) * 64 + ac0;           \
        A0 = *(const uint4*)(pa_ + 0);  A1 = *(const uint4*)(pa_ + 8);             \
        A2 = *(const uint4*)(pa_ + 16); A3 = *(const uint4*)(pa_ + 24);            \
        const ushort* pb_ = Brow + (size_t)arow * 512 + (KS) * 64 + ac0;           \
        B0 = *(const uint4*)(pb_ + 0);  B1 = *(const uint4*)(pb_ + 8);             \
        B2 = *(const uint4*)(pb_ + 16); B3 = *(const uint4*)(pb_ + 24);            \
    }

#define QG_STORE(CUR, A0, A1, A2, A3, B0, B1, B2, B3)            \
    {                                                            \
        ushort* la_ = &At[CUR][arow * 72 + ac0];                 \
        *(uint4*)(la_ + 0) = A0;  *(uint4*)(la_ + 8) = A1;       \
        *(uint4*)(la_ + 16) = A2; *(uint4*)(la_ + 24) = A3;      \
        ushort* lb_ = &Bt[CUR][arow * 72 + ac0];                 \
        *(uint4*)(lb_ + 0) = B0;  *(uint4*)(lb_ + 8) = B1;       \
        *(uint4*)(lb_ + 16) = B2; *(uint4*)(lb_ + 24) = B3;      \
    }

#define QG_COMPUTE(CUR)                                                                      \
    {                                                                                        \
        _Pragma("unroll") for (int kk = 0; kk < 2; ++kk) {                                   \
            bf16x8 af[4], bfr[4];                                                            \
            _Pragma("unroll") for (int r = 0; r < 4; ++r)                                    \
                af[r] = *(const bf16x8*)&At[CUR][(wr * 64 + r * 16 + ln) * 72 + kk * 32 + lg * 8]; \
            _Pragma("unroll") for (int cc = 0; cc < 4; ++cc)                                 \
                bfr[cc] = *(const bf16x8*)&Bt[CUR][(wc * 64 + cc * 16 + ln) * 72 + kk * 32 + lg * 8]; \
            _Pragma("unroll") for (int r = 0; r < 4; ++r)                                    \
                _Pragma("unroll") for (int cc = 0; cc < 4; ++cc)                             \
                    acc[r][cc] = __builtin_amdgcn_mfma_f32_16x16x32_bf16(af[r], bfr[cc],     \
                                                                         acc[r][cc], 0, 0, 0); \
        }                                                                                    \
    }

    uint4 pA0, pA1, pA2, pA3, pB0, pB1, pB2, pB3;
    uint4 qA0, qA1, qA2, qA3, qB0, qB1, qB2, qB3;
    QG_LOAD(0, pA0, pA1, pA2, pA3, pB0, pB1, pB2, pB3)
    QG_LOAD(1, qA0, qA1, qA2, qA3, qB0, qB1, qB2, qB3)
    QG_STORE(0, pA0, pA1, pA2, pA3, pB0, pB1, pB2, pB3)
    __syncthreads();
    for (int ks = 0; ks < 6; ks += 2) {
        QG_LOAD(ks + 2, pA0, pA1, pA2, pA3, pB0, pB1, pB2, pB3)
        QG_COMPUTE(0)
        QG_STORE(1, qA0, qA1, qA2, qA3, qB0, qB1, qB2, qB3)
        __syncthreads();
        QG_LOAD(ks + 3, qA0, qA1, qA2, qA3, qB0, qB1, qB2, qB3)
        QG_COMPUTE(1)
        QG_STORE(0, pA0, pA1, pA2, pA3, pB0, pB1, pB2, pB3)
        __syncthreads();
    }
    QG_COMPUTE(0)
    QG_STORE(1, qA0, qA1, qA2, qA3, qB0, qB1, qB2, qB3)
    __syncthreads();
    QG_COMPUTE(1)

    float bv[4];
#pragma unroll
    for (int c = 0; c < 4; ++c) bv[c] = bias[n0 + wc * 64 + c * 16 + ln];
#pragma unroll
    for (int r = 0; r < 4; ++r)
#pragma unroll
        for (int c = 0; c < 4; ++c)
#pragma unroll
            for (int q = 0; q < 4; ++q) {
                int row = m0 + wr * 64 + r * 16 + lg * 4 + q;
                int col = n0 + wc * 64 + c * 16 + ln;
                Qb[(size_t)row * 512 + col] = f2bf(acc[r][c][q] + bv[c]);
            }
}

// ---------------- sgemm: P = exp(mask(Q X^T)) -> packed tiles, LDS-bounce store (R15) ---------
__global__ __launch_bounds__(256, 3) void sgemm_kernel(const ushort* __restrict__ Qb,
                                                       const ushort* __restrict__ Xb,
                                                       ushort* __restrict__ Pb,
                                                       int g0, int G) {
    __shared__ ushort SMEM[20480];     // 40KB: K-loop = At[2]|Bt[2] (pitch 40); epilogue = P tile
#define SG_AT(C) (SMEM + (C) * 5120)
#define SG_BT(C) (SMEM + 10240 + (C) * 5120)
    int t  = threadIdx.x;
    int bL = blockIdx.x;
    int b  = g0 + bL;
    int c  = blockIdx.y;               // 0..135 (uniform work)
    int it = 0, base = 0;
    for (;;) { if (c < base + it + 1) break; base += it + 1; ++it; }
    int jt = c - base;

    int m0 = it << 7, n0 = jt << 7;
    int w  = t >> 6, l = t & 63, ln = l & 15, lg = l >> 4;
    int wr = w >> 1, wc = w & 1;

    const ushort* Arow = Qb + (size_t)(b * SEQ + m0) * 512;
    const ushort* Brow = Xb + (size_t)(b * SEQ + n0) * 512;

    f32x4 acc[4][4] = {};
    int srow = t >> 2;
    int sc8  = (t & 3) * 8;

#define SG_LOAD(KS, A0, A1, B0, B1)                                                \
    A0 = *(const uint4*)(Arow + (size_t)srow * 512 + (KS) * 32 + sc8);             \
    A1 = *(const uint4*)(Arow + (size_t)(64 + srow) * 512 + (KS) * 32 + sc8);      \
    B0 = *(const uint4*)(Brow + (size_t)srow * 512 + (KS) * 32 + sc8);             \
    B1 = *(const uint4*)(Brow + (size_t)(64 + srow) * 512 + (KS) * 32 + sc8);

#define SG_STORE(CUR, A0, A1, B0, B1)                       \
    {                                                       \
        *(uint4*)&SG_AT(CUR)[srow * 40 + sc8]        = A0;  \
        *(uint4*)&SG_AT(CUR)[(64 + srow) * 40 + sc8] = A1;  \
        *(uint4*)&SG_BT(CUR)[srow * 40 + sc8]        = B0;  \
        *(uint4*)&SG_BT(CUR)[(64 + srow) * 40 + sc8] = B1;  \
    }

#define SG_COMPUTE(CUR)                                                                    \
    {                                                                                      \
        bf16x8 af[4], bfr[4];                                                              \
        _Pragma("unroll") for (int r = 0; r < 4; ++r)                                      \
            af[r] = *(const bf16x8*)&SG_AT(CUR)[(wr * 64 + r * 16 + ln) * 40 + lg * 8];    \
        _Pragma("unroll") for (int cc = 0; cc < 4; ++cc)                                   \
            bfr[cc] = *(const bf16x8*)&SG_BT(CUR)[(wc * 64 + cc * 16 + ln) * 40 + lg * 8]; \
        _Pragma("unroll") for (int r = 0; r < 4; ++r)                                      \
            _Pragma("unroll") for (int cc = 0; cc < 4; ++cc)                               \
                acc[r][cc] = __builtin_amdgcn_mfma_f32_16x16x32_bf16(af[r], bfr[cc],       \
                                                                     acc[r][cc], 0, 0, 0); \
    }

    uint4 pA0, pA1, pB0, pB1, qA0, qA1, qB0, qB1;
    SG_LOAD(0, pA0, pA1, pB0, pB1)
    SG_LOAD(1, qA0, qA1, qB0, qB1)
    SG_STORE(0, pA0, pA1, pB0, pB1)
    __syncthreads();
    for (int ks = 0; ks < 14; ks += 2) {
        SG_LOAD(ks + 2, pA0, pA1, pB0, pB1)
        SG_COMPUTE(0)
        SG_STORE(1, qA0, qA1, qB0, qB1)
        __syncthreads();
        SG_LOAD(ks + 3, qA0, qA1, qB0, qB1)
        SG_COMPUTE(1)
        SG_STORE(0, pA0, pA1, pB0, pB1)
        __syncthreads();
    }
    SG_COMPUTE(0)
    SG_STORE(1, qA0, qA1, qB0, qB1)
    __syncthreads();
    SG_COMPUTE(1)
    __syncthreads();                   // LDS free -> reuse as P-tile bounce

    // mask + exp -> LDS P tile [128][128] bf16
#pragma unroll
    for (int r = 0; r < 4; ++r)
#pragma unroll
        for (int q = 0; q < 4; ++q) {
            int prow = wr * 64 + r * 16 + lg * 4 + q;      // local i
            int grow = m0 + prow;                          // in-batch i
#pragma unroll
            for (int cc = 0; cc < 4; ++cc) {
                int pcol = wc * 64 + cc * 16 + ln;
                int col  = n0 + pcol;                      // in-batch j
                float ex = (col < grow) ? __expf(acc[r][cc][q]) : 0.f;
                SMEM[prow * 128 + pcol] = f2bf(ex);
            }
        }
    __syncthreads();

    // coalesced copy-out: 8 x 16B per thread, conflict-free interleave
    ushort* ptile = Pb + ((size_t)c * G + bL) * 16384;
#pragma unroll
    for (int k2 = 0; k2 < 8; ++k2)
        *(uint4*)(ptile + k2 * 2048 + t * 8) = *(const uint4*)(SMEM + k2 * 2048 + t * 8);
}

// ---------------- pvgemm: out = (P @ X)/(den+1e-10), BK=64, pitch-68 LDS, 3 blocks/CU ---------
// Grid (G, 128): it = 15-(y>>3) heavy-first, ht = y&7 -> 64-col slice.
__global__ __launch_bounds__(256, 3) void pvgemm_kernel(const ushort* __restrict__ Pb,
                                                        const ushort* __restrict__ Xt,
                                                        float* __restrict__ out,
                                                        int g0, int G) {
    __shared__ ushort Ap[2][128 * 68];
    __shared__ ushort Bp[2][64 * 68];
    __shared__ float  dden[128];
    int t  = threadIdx.x;
    int bL = blockIdx.x;
    int b  = g0 + bL;
    int y  = blockIdx.y;
    int it = 15 - (y >> 3);
    int ht = y & 7;                    // 0..7
    int n0 = ht << 6;
    int m0 = it << 7;
    int Tit = (it * (it + 1)) >> 1;
    int nks = (it + 1) * 2;            // BK=64 steps

    int w = t >> 6, l = t & 63, ln = l & 15, lg = l >> 4;
    int wr = w >> 1, wc = w & 1;       // wave tile: rows wr*64.., cols wc*32..
    int arow = t >> 1;                 // A staging: 0..127
    int ac0  = (t & 1) * 32;
    int brow = t >> 2;                 // B staging: 0..63 (h index)
    int bc0  = (t & 3) * 16;           // j chunk

    const ushort* BrowX = Xt + ((size_t)b * DIM + n0) * SEQ;

    bf16x8 vones;
#pragma unroll
    for (int e = 0; e < 8; ++e) vones[e] = (__bf16)1.0f;

// step S covers K cols S*64..S*64+63; P tile = Tit + (S>>1), col half (S&1)*64
#define PV_LOAD(S, A0, A1, A2, A3, B0, B1)                                              \
    {                                                                                   \
        const ushort* pt_ = Pb + ((size_t)(Tit + ((S) >> 1)) * G + bL) * 16384          \
                            + ((S) & 1) * 64 + (size_t)arow * 128 + ac0;                \
        A0 = *(const uint4*)(pt_ + 0);  A1 = *(const uint4*)(pt_ + 8);                  \
        A2 = *(const uint4*)(pt_ + 16); A3 = *(const uint4*)(pt_ + 24);                 \
        const ushort* pb_ = BrowX + (size_t)brow * 2048 + (S) * 64 + bc0;               \
        B0 = *(const uint4*)(pb_ + 0);  B1 = *(const uint4*)(pb_ + 8);                  \
    }
#define PV_ST(CUR, A0, A1, A2, A3, B0, B1)                       \
    {                                                            \
        ushort* la_ = &Ap[CUR][arow * 68 + ac0];                 \
        *(uint4*)(la_ + 0) = A0;  *(uint4*)(la_ + 8) = A1;       \
        *(uint4*)(la_ + 16) = A2; *(uint4*)(la_ + 24) = A3;      \
        ushort* lb_ = &Bp[CUR][brow * 68 + bc0];                 \
        *(uint4*)(lb_ + 0) = B0;  *(uint4*)(lb_ + 8) = B1;       \
    }
// PV compute over 2 k-chunks; den rides MFMA pipe (rule-#20-safe literal indices)
#define PV_COMPUTE(CUR)                                                                     \
    {                                                                                       \
        _Pragma("unroll") for (int kk = 0; kk < 2; ++kk) {                                  \
            bf16x8 af[4], bfr[2];                                                           \
            _Pragma("unroll") for (int r = 0; r < 4; ++r)                                   \
                af[r] = *(const bf16x8*)&Ap[CUR][(wr * 64 + r * 16 + ln) * 68 + kk * 32 + lg * 8]; \
            _Pragma("unroll") for (int cc = 0; cc < 2; ++cc)                                \
                bfr[cc] = *(const bf16x8*)&Bp[CUR][(wc * 32 + cc * 16 + ln) * 68 + kk * 32 + lg * 8]; \
            if (wc == 0) {                                                                  \
                accd0 = __builtin_amdgcn_mfma_f32_16x16x32_bf16(af[0], vones, accd0, 0, 0, 0); \
                accd1 = __builtin_amdgcn_mfma_f32_16x16x32_bf16(af[1], vones, accd1, 0, 0, 0); \
            } else {                                                                        \
                accd0 = __builtin_amdgcn_mfma_f32_16x16x32_bf16(af[2], vones, accd0, 0, 0, 0); \
                accd1 = __builtin_amdgcn_mfma_f32_16x16x32_bf16(af[3], vones, accd1, 0, 0, 0); \
            }                                                                               \
            _Pragma("unroll") for (int r = 0; r < 4; ++r)                                   \
                _Pragma("unroll") for (int cc = 0; cc < 2; ++cc)                            \
                    acc[r][cc] = __builtin_amdgcn_mfma_f32_16x16x32_bf16(af[r], bfr[cc],    \
                                                                         acc[r][cc], 0, 0, 0); \
        }                                                                                   \
    }

    f32x4 acc[4][2] = {};
    f32x4 accd0 = {}, accd1 = {};

    uint4 pA0, pA1, pA2, pA3, pB0, pB1;
    uint4 qA0, qA1, qA2, qA3, qB0, qB1;
    PV_LOAD(0, pA0, pA1, pA2, pA3, pB0, pB1)
    PV_LOAD(1, qA0, qA1, qA2, qA3, qB0, qB1)
    PV_ST(0, pA0, pA1, pA2, pA3, pB0, pB1)
    __syncthreads();
    for (int ks = 0; ks < nks - 2; ks += 2) {
        PV_LOAD(ks + 2, pA0, pA1, pA2, pA3, pB0, pB1)
        PV_COMPUTE(0)
        PV_ST(1, qA0, qA1, qA2, qA3, qB0, qB1)
        __syncthreads();
        if (ks + 3 < nks) PV_LOAD(ks + 3, qA0, qA1, qA2, qA3, qB0, qB1)
        PV_COMPUTE(1)
        PV_ST(0, pA0, pA1, pA2, pA3, pB0, pB1)
        __syncthreads();
    }
    PV_COMPUTE(0)
    PV_ST(1, qA0, qA1, qA2, qA3, qB0, qB1)
    __syncthreads();
    PV_COMPUTE(1)

    // publish den: every output column of accd equals the rowsum; lane ln==0 writes.
    if (ln == 0) {
#pragma unroll
        for (int q = 0; q < 4; ++q) {
            dden[wr * 64 + (wc * 2) * 16 + lg * 4 + q]     = accd0[q];
            dden[wr * 64 + (wc * 2 + 1) * 16 + lg * 4 + q] = accd1[q];
        }
    }
    __syncthreads();

#pragma unroll
    for (int r = 0; r < 4; ++r)
#pragma unroll
        for (int q = 0; q < 4; ++q) {
            int lrow = wr * 64 + r * 16 + lg * 4 + q;
            int row  = m0 + lrow;
            float inv = 1.0f / (dden[lrow] + 1e-10f);
            size_t o = (size_t)(b * SEQ + row) * 512;
#pragma unroll
            for (int cc = 0; cc < 2; ++cc)
                out[o + n0 + wc * 32 + cc * 16 + ln] = acc[r][cc][q] * inv;
        }
}

extern "C" void kernel_launch(void* const* d_in, const int* in_sizes, int n_in,
                              void* d_out, int out_size, void* d_ws, size_t ws_size,
                              hipStream_t stream) {
    const float* X    = (const float*)d_in[0];
    const float* W    = (const float*)d_in[1];
    const float* bias = (const float*)d_in[2];
    float* out = (float*)d_out;

    // ws layout (bytes): Xb[16.78M] | Xt[16.78M] | Qb[16.78M] | Wb[0.52M] | Pb[G*4.46M]
    ushort* ws = (ushort*)d_ws;
    ushort* Xb = ws;
    ushort* Xt = ws + 8388608;
    ushort* Qb = ws + 16777216;
    ushort* Wb = ws + 25165824;
    ushort* Pb = (ushort*)((char*)d_ws + 50855936);

    size_t avail = (ws_size > 50855936) ? (ws_size - 50855936) : 0;
    int G = 1;
    while (G < 8 && (size_t)(G * 2) * 4456448 <= avail) G *= 2;

    prep_kernel<<<dim3(8320), dim3(256), 0, stream>>>(X, Xb, Xt, W, Wb);
    qgemm_kernel<<<dim3(512), dim3(256), 0, stream>>>(Xb, Wb, bias, Qb);
    for (int g0 = 0; g0 < BATCH; g0 += G) {
        sgemm_kernel<<<dim3(G, 136), dim3(256), 0, stream>>>(Qb, Xb, Pb, g0, G);
        pvgemm_kernel<<<dim3(G, 128), dim3(256), 0, stream>>>(Pb, Xt, out, g0, G);
    }
}

// Round 19
// 90.696 us; speedup vs baseline: 1.4534x; 1.4534x over previous
//
#include <hip/hip_runtime.h>
#include <hip/hip_bf16.h>

// B=8, S=2048, H=512. out[b,i,:] = sum_{j<i} exp(q_i.x_j) x_j / (sum_{j<i} exp(q_i.x_j) + 1e-10)
// q = X @ W^T + b.
// R19: R16 base; pvgemm -> pitch-64 LDS with XOR-swizzled 16B chunks (chunk ^= row&7):
//      rows stay 128B-aligned (ds_*_b128 legal, unlike R18's pitch-68), 49.7KB -> 3 blocks/CU.
//      Grid (G,128) heavy-first (R18 proved 3-residency with this grid). BK=64 + den-MFMA kept.
#define BATCH 8
#define SEQ   2048
#define DIM   512

typedef __bf16 bf16x8 __attribute__((ext_vector_type(8)));
typedef float  f32x4  __attribute__((ext_vector_type(4)));

__device__ __forceinline__ ushort f2bf(float f) {
    union { float f; unsigned u; } c; c.f = f;
    unsigned u = c.u;
    u += 0x7fffu + ((u >> 16) & 1u);   // round-to-nearest-even
    return (ushort)(u >> 16);
}

// ---------------- prep: X f32 -> Xb bf16 + Xt bf16 (transposed); tail blocks do W->bf16 -------
__global__ __launch_bounds__(256) void prep_kernel(const float* __restrict__ X,
                                                   ushort* __restrict__ Xb,
                                                   ushort* __restrict__ Xt,
                                                   const float* __restrict__ W,
                                                   ushort* __restrict__ Wb) {
    __shared__ ushort T[32 * 33];
    int t   = threadIdx.x;
    int bid = blockIdx.x;              // 8192 X-blocks + 128 W-blocks
    if (bid >= 8192) {
        int gt = (bid - 8192) * 256 + t;
        size_t base = (size_t)gt * 8;
        float4 a = *(const float4*)(W + base);
        float4 c = *(const float4*)(W + base + 4);
        ushort4 lo, hi;
        lo.x = f2bf(a.x); lo.y = f2bf(a.y); lo.z = f2bf(a.z); lo.w = f2bf(a.w);
        hi.x = f2bf(c.x); hi.y = f2bf(c.y); hi.z = f2bf(c.z); hi.w = f2bf(c.w);
        *(ushort4*)(Wb + base)     = lo;
        *(ushort4*)(Wb + base + 4) = hi;
        return;
    }
    int b   = bid >> 10;
    int st  = (bid >> 4) & 63;
    int ht  = bid & 15;
    int s0 = st * 32, h0 = ht * 32;

    int r  = t >> 3;
    int c4 = (t & 7) * 4;
    size_t src = ((size_t)(b * SEQ + s0 + r)) * DIM + h0 + c4;
    float4 v = *(const float4*)(X + src);
    ushort u0 = f2bf(v.x), u1 = f2bf(v.y), u2 = f2bf(v.z), u3 = f2bf(v.w);
    ushort4 uv; uv.x = u0; uv.y = u1; uv.z = u2; uv.w = u3;
    *(ushort4*)(Xb + src) = uv;
    T[(c4 + 0) * 33 + r] = u0;
    T[(c4 + 1) * 33 + r] = u1;
    T[(c4 + 2) * 33 + r] = u2;
    T[(c4 + 3) * 33 + r] = u3;
    __syncthreads();
    int hh = t >> 3;
    int sc = (t & 7) * 4;
    ushort4 w;
    w.x = T[hh * 33 + sc + 0];
    w.y = T[hh * 33 + sc + 1];
    w.z = T[hh * 33 + sc + 2];
    w.w = T[hh * 33 + sc + 3];
    *(ushort4*)(Xt + ((size_t)(b * DIM + h0 + hh)) * SEQ + s0 + sc) = w;
}

// ---------------- qgemm: Qb = bf16(Xb @ Wb^T + bias), BK=64, depth-2 ----------------
__global__ __launch_bounds__(256, 2) void qgemm_kernel(const ushort* __restrict__ Xb,
                                                       const ushort* __restrict__ Wb,
                                                       const float* __restrict__ bias,
                                                       ushort* __restrict__ Qb) {
    __shared__ ushort At[2][128 * 72];
    __shared__ ushort Bt[2][128 * 72];
    int t   = threadIdx.x;
    int bid = blockIdx.x;              // 128 mtiles * 4 ntiles
    int mt = bid >> 2, nt = bid & 3;
    int m0 = mt << 7, n0 = nt << 7;
    int w  = t >> 6, l = t & 63, ln = l & 15, lg = l >> 4;
    int wr = w >> 1, wc = w & 1;

    f32x4 acc[4][4] = {};
    int arow = t >> 1;                 // 0..127
    int ac0  = (t & 1) * 32;           // 0 or 32

    const ushort* Arow = Xb + (size_t)m0 * 512;
    const ushort* Brow = Wb + (size_t)n0 * 512;

#define QG_LOAD(KS, A0, A1, A2, A3, B0, B1, B2, B3)                                \
    {                                                                              \
        const ushort* pa_ = Arow + (size_t)arow * 512 + (KS) * 64 + ac0;           \
        A0 = *(const uint4*)(pa_ + 0);  A1 = *(const uint4*)(pa_ + 8);             \
        A2 = *(const uint4*)(pa_ + 16); A3 = *(const uint4*)(pa_ + 24);            \
        const ushort* pb_ = Brow + (size_t)arow * 512 + (KS) * 64 + ac0;           \
        B0 = *(const uint4*)(pb_ + 0);  B1 = *(const uint4*)(pb_ + 8);             \
        B2 = *(const uint4*)(pb_ + 16); B3 = *(const uint4*)(pb_ + 24);            \
    }

#define QG_STORE(CUR, A0, A1, A2, A3, B0, B1, B2, B3)            \
    {                                                            \
        ushort* la_ = &At[CUR][arow * 72 + ac0];                 \
        *(uint4*)(la_ + 0) = A0;  *(uint4*)(la_ + 8) = A1;       \
        *(uint4*)(la_ + 16) = A2; *(uint4*)(la_ + 24) = A3;      \
        ushort* lb_ = &Bt[CUR][arow * 72 + ac0];                 \
        *(uint4*)(lb_ + 0) = B0;  *(uint4*)(lb_ + 8) = B1;       \
        *(uint4*)(lb_ + 16) = B2; *(uint4*)(lb_ + 24) = B3;      \
    }

#define QG_COMPUTE(CUR)                                                                      \
    {                                                                                        \
        _Pragma("unroll") for (int kk = 0; kk < 2; ++kk) {                                   \
            bf16x8 af[4], bfr[4];                                                            \
            _Pragma("unroll") for (int r = 0; r < 4; ++r)                                    \
                af[r] = *(const bf16x8*)&At[CUR][(wr * 64 + r * 16 + ln) * 72 + kk * 32 + lg * 8]; \
            _Pragma("unroll") for (int cc = 0; cc < 4; ++cc)                                 \
                bfr[cc] = *(const bf16x8*)&Bt[CUR][(wc * 64 + cc * 16 + ln) * 72 + kk * 32 + lg * 8]; \
            _Pragma("unroll") for (int r = 0; r < 4; ++r)                                    \
                _Pragma("unroll") for (int cc = 0; cc < 4; ++cc)                             \
                    acc[r][cc] = __builtin_amdgcn_mfma_f32_16x16x32_bf16(af[r], bfr[cc],     \
                                                                         acc[r][cc], 0, 0, 0); \
        }                                                                                    \
    }

    uint4 pA0, pA1, pA2, pA3, pB0, pB1, pB2, pB3;
    uint4 qA0, qA1, qA2, qA3, qB0, qB1, qB2, qB3;
    QG_LOAD(0, pA0, pA1, pA2, pA3, pB0, pB1, pB2, pB3)
    QG_LOAD(1, qA0, qA1, qA2, qA3, qB0, qB1, qB2, qB3)
    QG_STORE(0, pA0, pA1, pA2, pA3, pB0, pB1, pB2, pB3)
    __syncthreads();
    for (int ks = 0; ks < 6; ks += 2) {
        QG_LOAD(ks + 2, pA0, pA1, pA2, pA3, pB0, pB1, pB2, pB3)
        QG_COMPUTE(0)
        QG_STORE(1, qA0, qA1, qA2, qA3, qB0, qB1, qB2, qB3)
        __syncthreads();
        QG_LOAD(ks + 3, qA0, qA1, qA2, qA3, qB0, qB1, qB2, qB3)
        QG_COMPUTE(1)
        QG_STORE(0, pA0, pA1, pA2, pA3, pB0, pB1, pB2, pB3)
        __syncthreads();
    }
    QG_COMPUTE(0)
    QG_STORE(1, qA0, qA1, qA2, qA3, qB0, qB1, qB2, qB3)
    __syncthreads();
    QG_COMPUTE(1)

    float bv[4];
#pragma unroll
    for (int c = 0; c < 4; ++c) bv[c] = bias[n0 + wc * 64 + c * 16 + ln];
#pragma unroll
    for (int r = 0; r < 4; ++r)
#pragma unroll
        for (int c = 0; c < 4; ++c)
#pragma unroll
            for (int q = 0; q < 4; ++q) {
                int row = m0 + wr * 64 + r * 16 + lg * 4 + q;
                int col = n0 + wc * 64 + c * 16 + ln;
                Qb[(size_t)row * 512 + col] = f2bf(acc[r][c][q] + bv[c]);
            }
}

// ---------------- sgemm: P = exp(mask(Q X^T)) -> packed tiles, LDS-bounce store (R15) ---------
__global__ __launch_bounds__(256, 3) void sgemm_kernel(const ushort* __restrict__ Qb,
                                                       const ushort* __restrict__ Xb,
                                                       ushort* __restrict__ Pb,
                                                       int g0, int G) {
    __shared__ ushort SMEM[20480];     // 40KB: K-loop = At[2]|Bt[2] (pitch 40); epilogue = P tile
#define SG_AT(C) (SMEM + (C) * 5120)
#define SG_BT(C) (SMEM + 10240 + (C) * 5120)
    int t  = threadIdx.x;
    int bL = blockIdx.x;
    int b  = g0 + bL;
    int c  = blockIdx.y;               // 0..135 (uniform work)
    int it = 0, base = 0;
    for (;;) { if (c < base + it + 1) break; base += it + 1; ++it; }
    int jt = c - base;

    int m0 = it << 7, n0 = jt << 7;
    int w  = t >> 6, l = t & 63, ln = l & 15, lg = l >> 4;
    int wr = w >> 1, wc = w & 1;

    const ushort* Arow = Qb + (size_t)(b * SEQ + m0) * 512;
    const ushort* Brow = Xb + (size_t)(b * SEQ + n0) * 512;

    f32x4 acc[4][4] = {};
    int srow = t >> 2;
    int sc8  = (t & 3) * 8;

#define SG_LOAD(KS, A0, A1, B0, B1)                                                \
    A0 = *(const uint4*)(Arow + (size_t)srow * 512 + (KS) * 32 + sc8);             \
    A1 = *(const uint4*)(Arow + (size_t)(64 + srow) * 512 + (KS) * 32 + sc8);      \
    B0 = *(const uint4*)(Brow + (size_t)srow * 512 + (KS) * 32 + sc8);             \
    B1 = *(const uint4*)(Brow + (size_t)(64 + srow) * 512 + (KS) * 32 + sc8);

#define SG_STORE(CUR, A0, A1, B0, B1)                       \
    {                                                       \
        *(uint4*)&SG_AT(CUR)[srow * 40 + sc8]        = A0;  \
        *(uint4*)&SG_AT(CUR)[(64 + srow) * 40 + sc8] = A1;  \
        *(uint4*)&SG_BT(CUR)[srow * 40 + sc8]        = B0;  \
        *(uint4*)&SG_BT(CUR)[(64 + srow) * 40 + sc8] = B1;  \
    }

#define SG_COMPUTE(CUR)                                                                    \
    {                                                                                      \
        bf16x8 af[4], bfr[4];                                                              \
        _Pragma("unroll") for (int r = 0; r < 4; ++r)                                      \
            af[r] = *(const bf16x8*)&SG_AT(CUR)[(wr * 64 + r * 16 + ln) * 40 + lg * 8];    \
        _Pragma("unroll") for (int cc = 0; cc < 4; ++cc)                                   \
            bfr[cc] = *(const bf16x8*)&SG_BT(CUR)[(wc * 64 + cc * 16 + ln) * 40 + lg * 8]; \
        _Pragma("unroll") for (int r = 0; r < 4; ++r)                                      \
            _Pragma("unroll") for (int cc = 0; cc < 4; ++cc)                               \
                acc[r][cc] = __builtin_amdgcn_mfma_f32_16x16x32_bf16(af[r], bfr[cc],       \
                                                                     acc[r][cc], 0, 0, 0); \
    }

    uint4 pA0, pA1, pB0, pB1, qA0, qA1, qB0, qB1;
    SG_LOAD(0, pA0, pA1, pB0, pB1)
    SG_LOAD(1, qA0, qA1, qB0, qB1)
    SG_STORE(0, pA0, pA1, pB0, pB1)
    __syncthreads();
    for (int ks = 0; ks < 14; ks += 2) {
        SG_LOAD(ks + 2, pA0, pA1, pB0, pB1)
        SG_COMPUTE(0)
        SG_STORE(1, qA0, qA1, qB0, qB1)
        __syncthreads();
        SG_LOAD(ks + 3, qA0, qA1, qB0, qB1)
        SG_COMPUTE(1)
        SG_STORE(0, pA0, pA1, pB0, pB1)
        __syncthreads();
    }
    SG_COMPUTE(0)
    SG_STORE(1, qA0, qA1, qB0, qB1)
    __syncthreads();
    SG_COMPUTE(1)
    __syncthreads();                   // LDS free -> reuse as P-tile bounce

    // mask + exp -> LDS P tile [128][128] bf16
#pragma unroll
    for (int r = 0; r < 4; ++r)
#pragma unroll
        for (int q = 0; q < 4; ++q) {
            int prow = wr * 64 + r * 16 + lg * 4 + q;      // local i
            int grow = m0 + prow;                          // in-batch i
#pragma unroll
            for (int cc = 0; cc < 4; ++cc) {
                int pcol = wc * 64 + cc * 16 + ln;
                int col  = n0 + pcol;                      // in-batch j
                float ex = (col < grow) ? __expf(acc[r][cc][q]) : 0.f;
                SMEM[prow * 128 + pcol] = f2bf(ex);
            }
        }
    __syncthreads();

    // coalesced copy-out: 8 x 16B per thread, conflict-free interleave
    ushort* ptile = Pb + ((size_t)c * G + bL) * 16384;
#pragma unroll
    for (int k2 = 0; k2 < 8; ++k2)
        *(uint4*)(ptile + k2 * 2048 + t * 8) = *(const uint4*)(SMEM + k2 * 2048 + t * 8);
}

// ---------------- pvgemm: out = (P @ X)/(den+1e-10), BK=64, swizzled pitch-64, 3 blk/CU -------
// Grid (G, 128): it = 15-(y>>3) heavy-first, ht = y&7 -> 64-col slice.
// LDS 16B-chunk XOR swizzle: chunk' = chunk ^ (row & 7); rows 128B so b128 stays legal.
__global__ __launch_bounds__(256, 3) void pvgemm_kernel(const ushort* __restrict__ Pb,
                                                        const ushort* __restrict__ Xt,
                                                        float* __restrict__ out,
                                                        int g0, int G) {
    __shared__ ushort Ap[2][128 * 64];
    __shared__ ushort Bp[2][64 * 64];
    __shared__ float  dden[128];
    int t  = threadIdx.x;
    int bL = blockIdx.x;
    int b  = g0 + bL;
    int y  = blockIdx.y;
    int it = 15 - (y >> 3);
    int ht = y & 7;                    // 0..7
    int n0 = ht << 6;
    int m0 = it << 7;
    int Tit = (it * (it + 1)) >> 1;
    int nks = (it + 1) * 2;            // BK=64 steps

    int w = t >> 6, l = t & 63, ln = l & 15, lg = l >> 4;
    int wr = w >> 1, wc = w & 1;       // wave tile: rows wr*64.., cols wc*32..
    int arow = t >> 1;                 // A staging: 0..127
    int acb  = (t & 1) * 4;            // A chunk base (16B chunks)
    int brow = t >> 2;                 // B staging: 0..63 (h index)
    int bcb  = (t & 3) * 2;            // B chunk base

    // swizzled staging chunk offsets (shorts)
    int aswz0 = ((acb + 0) ^ (arow & 7)) * 8;
    int aswz1 = ((acb + 1) ^ (arow & 7)) * 8;
    int aswz2 = ((acb + 2) ^ (arow & 7)) * 8;
    int aswz3 = ((acb + 3) ^ (arow & 7)) * 8;
    int bswz0 = ((bcb + 0) ^ (brow & 7)) * 8;
    int bswz1 = ((bcb + 1) ^ (brow & 7)) * 8;
    // swizzled read chunk offsets: chunk = kk*4 + lg, row&7 = ln&7
    int rsw0 = ((0 * 4 + lg) ^ (ln & 7)) * 8;   // kk=0
    int rsw1 = ((1 * 4 + lg) ^ (ln & 7)) * 8;   // kk=1

    const ushort* BrowX = Xt + ((size_t)b * DIM + n0) * SEQ;

    bf16x8 vones;
#pragma unroll
    for (int e = 0; e < 8; ++e) vones[e] = (__bf16)1.0f;

// step S covers K cols S*64..S*64+63; P tile = Tit + (S>>1), col half (S&1)*64
#define PV_LOAD(S, A0, A1, A2, A3, B0, B1)                                              \
    {                                                                                   \
        const ushort* pt_ = Pb + ((size_t)(Tit + ((S) >> 1)) * G + bL) * 16384          \
                            + ((S) & 1) * 64 + (size_t)arow * 128 + acb * 8;            \
        A0 = *(const uint4*)(pt_ + 0);  A1 = *(const uint4*)(pt_ + 8);                  \
        A2 = *(const uint4*)(pt_ + 16); A3 = *(const uint4*)(pt_ + 24);                 \
        const ushort* pb_ = BrowX + (size_t)brow * 2048 + (S) * 64 + bcb * 8;           \
        B0 = *(const uint4*)(pb_ + 0);  B1 = *(const uint4*)(pb_ + 8);                  \
    }
#define PV_ST(CUR, A0, A1, A2, A3, B0, B1)                       \
    {                                                            \
        ushort* la_ = &Ap[CUR][arow * 64];                       \
        *(uint4*)(la_ + aswz0) = A0;  *(uint4*)(la_ + aswz1) = A1; \
        *(uint4*)(la_ + aswz2) = A2;  *(uint4*)(la_ + aswz3) = A3; \
        ushort* lb_ = &Bp[CUR][brow * 64];                       \
        *(uint4*)(lb_ + bswz0) = B0;  *(uint4*)(lb_ + bswz1) = B1; \
    }
// PV compute over 2 k-chunks; den rides MFMA pipe (rule-#20-safe literal indices)
#define PV_COMPUTE(CUR)                                                                     \
    {                                                                                       \
        {                                                                                   \
            bf16x8 af[4], bfr[2];                                                           \
            _Pragma("unroll") for (int r = 0; r < 4; ++r)                                   \
                af[r] = *(const bf16x8*)&Ap[CUR][(wr * 64 + r * 16 + ln) * 64 + rsw0];      \
            _Pragma("unroll") for (int cc = 0; cc < 2; ++cc)                                \
                bfr[cc] = *(const bf16x8*)&Bp[CUR][(wc * 32 + cc * 16 + ln) * 64 + rsw0];   \
            if (wc == 0) {                                                                  \
                accd0 = __builtin_amdgcn_mfma_f32_16x16x32_bf16(af[0], vones, accd0, 0, 0, 0); \
                accd1 = __builtin_amdgcn_mfma_f32_16x16x32_bf16(af[1], vones, accd1, 0, 0, 0); \
            } else {                                                                        \
                accd0 = __builtin_amdgcn_mfma_f32_16x16x32_bf16(af[2], vones, accd0, 0, 0, 0); \
                accd1 = __builtin_amdgcn_mfma_f32_16x16x32_bf16(af[3], vones, accd1, 0, 0, 0); \
            }                                                                               \
            _Pragma("unroll") for (int r = 0; r < 4; ++r)                                   \
                _Pragma("unroll") for (int cc = 0; cc < 2; ++cc)                            \
                    acc[r][cc] = __builtin_amdgcn_mfma_f32_16x16x32_bf16(af[r], bfr[cc],    \
                                                                         acc[r][cc], 0, 0, 0); \
        }                                                                                   \
        {                                                                                   \
            bf16x8 af[4], bfr[2];                                                           \
            _Pragma("unroll") for (int r = 0; r < 4; ++r)                                   \
                af[r] = *(const bf16x8*)&Ap[CUR][(wr * 64 + r * 16 + ln) * 64 + rsw1];      \
            _Pragma("unroll") for (int cc = 0; cc < 2; ++cc)                                \
                bfr[cc] = *(const bf16x8*)&Bp[CUR][(wc * 32 + cc * 16 + ln) * 64 + rsw1];   \
            if (wc == 0) {                                                                  \
                accd0 = __builtin_amdgcn_mfma_f32_16x16x32_bf16(af[0], vones, accd0, 0, 0, 0); \
                accd1 = __builtin_amdgcn_mfma_f32_16x16x32_bf16(af[1], vones, accd1, 0, 0, 0); \
            } else {                                                                        \
                accd0 = __builtin_amdgcn_mfma_f32_16x16x32_bf16(af[2], vones, accd0, 0, 0, 0); \
                accd1 = __builtin_amdgcn_mfma_f32_16x16x32_bf16(af[3], vones, accd1, 0, 0, 0); \
            }                                                                               \
            _Pragma("unroll") for (int r = 0; r < 4; ++r)                                   \
                _Pragma("unroll") for (int cc = 0; cc < 2; ++cc)                            \
                    acc[r][cc] = __builtin_amdgcn_mfma_f32_16x16x32_bf16(af[r], bfr[cc],    \
                                                                         acc[r][cc], 0, 0, 0); \
        }                                                                                   \
    }

    f32x4 acc[4][2] = {};
    f32x4 accd0 = {}, accd1 = {};

    uint4 pA0, pA1, pA2, pA3, pB0, pB1;
    uint4 qA0, qA1, qA2, qA3, qB0, qB1;
    PV_LOAD(0, pA0, pA1, pA2, pA3, pB0, pB1)
    PV_LOAD(1, qA0, qA1, qA2, qA3, qB0, qB1)
    PV_ST(0, pA0, pA1, pA2, pA3, pB0, pB1)
    __syncthreads();
    for (int ks = 0; ks < nks - 2; ks += 2) {
        PV_LOAD(ks + 2, pA0, pA1, pA2, pA3, pB0, pB1)
        PV_COMPUTE(0)
        PV_ST(1, qA0, qA1, qA2, qA3, qB0, qB1)
        __syncthreads();
        if (ks + 3 < nks) PV_LOAD(ks + 3, qA0, qA1, qA2, qA3, qB0, qB1)
        PV_COMPUTE(1)
        PV_ST(0, pA0, pA1, pA2, pA3, pB0, pB1)
        __syncthreads();
    }
    PV_COMPUTE(0)
    PV_ST(1, qA0, qA1, qA2, qA3, qB0, qB1)
    __syncthreads();
    PV_COMPUTE(1)

    // publish den: every output column of accd equals the rowsum; lane ln==0 writes.
    if (ln == 0) {
#pragma unroll
        for (int q = 0; q < 4; ++q) {
            dden[wr * 64 + (wc * 2) * 16 + lg * 4 + q]     = accd0[q];
            dden[wr * 64 + (wc * 2 + 1) * 16 + lg * 4 + q] = accd1[q];
        }
    }
    __syncthreads();

#pragma unroll
    for (int r = 0; r < 4; ++r)
#pragma unroll
        for (int q = 0; q < 4; ++q) {
            int lrow = wr * 64 + r * 16 + lg * 4 + q;
            int row  = m0 + lrow;
            float inv = 1.0f / (dden[lrow] + 1e-10f);
            size_t o = (size_t)(b * SEQ + row) * 512;
#pragma unroll
            for (int cc = 0; cc < 2; ++cc)
                out[o + n0 + wc * 32 + cc * 16 + ln] = acc[r][cc][q] * inv;
        }
}

extern "C" void kernel_launch(void* const* d_in, const int* in_sizes, int n_in,
                              void* d_out, int out_size, void* d_ws, size_t ws_size,
                              hipStream_t stream) {
    const float* X    = (const float*)d_in[0];
    const float* W    = (const float*)d_in[1];
    const float* bias = (const float*)d_in[2];
    float* out = (float*)d_out;

    // ws layout (bytes): Xb[16.78M] | Xt[16.78M] | Qb[16.78M] | Wb[0.52M] | Pb[G*4.46M]
    ushort* ws = (ushort*)d_ws;
    ushort* Xb = ws;
    ushort* Xt = ws + 8388608;
    ushort* Qb = ws + 16777216;
    ushort* Wb = ws + 25165824;
    ushort* Pb = (ushort*)((char*)d_ws + 50855936);

    size_t avail = (ws_size > 50855936) ? (ws_size - 50855936) : 0;
    int G = 1;
    while (G < 8 && (size_t)(G * 2) * 4456448 <= avail) G *= 2;

    prep_kernel<<<dim3(8320), dim3(256), 0, stream>>>(X, Xb, Xt, W, Wb);
    qgemm_kernel<<<dim3(512), dim3(256), 0, stream>>>(Xb, Wb, bias, Qb);
    for (int g0 = 0; g0 < BATCH; g0 += G) {
        sgemm_kernel<<<dim3(G, 136), dim3(256), 0, stream>>>(Qb, Xb, Pb, g0, G);
        pvgemm_kernel<<<dim3(G, 128), dim3(256), 0, stream>>>(Pb, Xt, out, g0, G);
    }
}

// Round 20
// 89.950 us; speedup vs baseline: 1.4655x; 1.0083x over previous
//
#include <hip/hip_runtime.h>
#include <hip/hip_bf16.h>

// B=8, S=2048, H=512. out[b,i,:] = sum_{j<i} exp(q_i.x_j) x_j / (sum_{j<i} exp(q_i.x_j) + 1e-10)
// q = X @ W^T + b.
// R20: R19 + (1) pvgemm nontemporal out stores (64MB f32 written-once -> don't evict P/Xt
//      from L2); (2) sgemm P-bounce pitch 128->136 shorts (write conflicts 4-way -> 2-way free,
//      rows stay 16B-aligned; copy-out remapped, still fully coalesced).
#define BATCH 8
#define SEQ   2048
#define DIM   512

typedef __bf16 bf16x8 __attribute__((ext_vector_type(8)));
typedef float  f32x4  __attribute__((ext_vector_type(4)));

__device__ __forceinline__ ushort f2bf(float f) {
    union { float f; unsigned u; } c; c.f = f;
    unsigned u = c.u;
    u += 0x7fffu + ((u >> 16) & 1u);   // round-to-nearest-even
    return (ushort)(u >> 16);
}

// ---------------- prep: X f32 -> Xb bf16 + Xt bf16 (transposed); tail blocks do W->bf16 -------
__global__ __launch_bounds__(256) void prep_kernel(const float* __restrict__ X,
                                                   ushort* __restrict__ Xb,
                                                   ushort* __restrict__ Xt,
                                                   const float* __restrict__ W,
                                                   ushort* __restrict__ Wb) {
    __shared__ ushort T[32 * 33];
    int t   = threadIdx.x;
    int bid = blockIdx.x;              // 8192 X-blocks + 128 W-blocks
    if (bid >= 8192) {
        int gt = (bid - 8192) * 256 + t;
        size_t base = (size_t)gt * 8;
        float4 a = *(const float4*)(W + base);
        float4 c = *(const float4*)(W + base + 4);
        ushort4 lo, hi;
        lo.x = f2bf(a.x); lo.y = f2bf(a.y); lo.z = f2bf(a.z); lo.w = f2bf(a.w);
        hi.x = f2bf(c.x); hi.y = f2bf(c.y); hi.z = f2bf(c.z); hi.w = f2bf(c.w);
        *(ushort4*)(Wb + base)     = lo;
        *(ushort4*)(Wb + base + 4) = hi;
        return;
    }
    int b   = bid >> 10;
    int st  = (bid >> 4) & 63;
    int ht  = bid & 15;
    int s0 = st * 32, h0 = ht * 32;

    int r  = t >> 3;
    int c4 = (t & 7) * 4;
    size_t src = ((size_t)(b * SEQ + s0 + r)) * DIM + h0 + c4;
    float4 v = *(const float4*)(X + src);
    ushort u0 = f2bf(v.x), u1 = f2bf(v.y), u2 = f2bf(v.z), u3 = f2bf(v.w);
    ushort4 uv; uv.x = u0; uv.y = u1; uv.z = u2; uv.w = u3;
    *(ushort4*)(Xb + src) = uv;
    T[(c4 + 0) * 33 + r] = u0;
    T[(c4 + 1) * 33 + r] = u1;
    T[(c4 + 2) * 33 + r] = u2;
    T[(c4 + 3) * 33 + r] = u3;
    __syncthreads();
    int hh = t >> 3;
    int sc = (t & 7) * 4;
    ushort4 w;
    w.x = T[hh * 33 + sc + 0];
    w.y = T[hh * 33 + sc + 1];
    w.z = T[hh * 33 + sc + 2];
    w.w = T[hh * 33 + sc + 3];
    *(ushort4*)(Xt + ((size_t)(b * DIM + h0 + hh)) * SEQ + s0 + sc) = w;
}

// ---------------- qgemm: Qb = bf16(Xb @ Wb^T + bias), BK=64, depth-2 ----------------
__global__ __launch_bounds__(256, 2) void qgemm_kernel(const ushort* __restrict__ Xb,
                                                       const ushort* __restrict__ Wb,
                                                       const float* __restrict__ bias,
                                                       ushort* __restrict__ Qb) {
    __shared__ ushort At[2][128 * 72];
    __shared__ ushort Bt[2][128 * 72];
    int t   = threadIdx.x;
    int bid = blockIdx.x;              // 128 mtiles * 4 ntiles
    int mt = bid >> 2, nt = bid & 3;
    int m0 = mt << 7, n0 = nt << 7;
    int w  = t >> 6, l = t & 63, ln = l & 15, lg = l >> 4;
    int wr = w >> 1, wc = w & 1;

    f32x4 acc[4][4] = {};
    int arow = t >> 1;                 // 0..127
    int ac0  = (t & 1) * 32;           // 0 or 32

    const ushort* Arow = Xb + (size_t)m0 * 512;
    const ushort* Brow = Wb + (size_t)n0 * 512;

#define QG_LOAD(KS, A0, A1, A2, A3, B0, B1, B2, B3)                                \
    {                                                                              \
        const ushort* pa_ = Arow + (size_t)arow * 512 + (KS) * 64 + ac0;           \
        A0 = *(const uint4*)(pa_ + 0);  A1 = *(const uint4*)(pa_ + 8);             \
        A2 = *(const uint4*)(pa_ + 16); A3 = *(const uint4*)(pa_ + 24);            \
        const ushort* pb_ = Brow + (size_t)arow * 512 + (KS) * 64 + ac0;           \
        B0 = *(const uint4*)(pb_ + 0);  B1 = *(const uint4*)(pb_ + 8);             \
        B2 = *(const uint4*)(pb_ + 16); B3 = *(const uint4*)(pb_ + 24);            \
    }

#define QG_STORE(CUR, A0, A1, A2, A3, B0, B1, B2, B3)            \
    {                                                            \
        ushort* la_ = &At[CUR][arow * 72 + ac0];                 \
        *(uint4*)(la_ + 0) = A0;  *(uint4*)(la_ + 8) = A1;       \
        *(uint4*)(la_ + 16) = A2; *(uint4*)(la_ + 24) = A3;      \
        ushort* lb_ = &Bt[CUR][arow * 72 + ac0];                 \
        *(uint4*)(lb_ + 0) = B0;  *(uint4*)(lb_ + 8) = B1;       \
        *(uint4*)(lb_ + 16) = B2; *(uint4*)(lb_ + 24) = B3;      \
    }

#define QG_COMPUTE(CUR)                                                                      \
    {                                                                                        \
        _Pragma("unroll") for (int kk = 0; kk < 2; ++kk) {                                   \
            bf16x8 af[4], bfr[4];                                                            \
            _Pragma("unroll") for (int r = 0; r < 4; ++r)                                    \
                af[r] = *(const bf16x8*)&At[CUR][(wr * 64 + r * 16 + ln) * 72 + kk * 32 + lg * 8]; \
            _Pragma("unroll") for (int cc = 0; cc < 4; ++cc)                                 \
                bfr[cc] = *(const bf16x8*)&Bt[CUR][(wc * 64 + cc * 16 + ln) * 72 + kk * 32 + lg * 8]; \
            _Pragma("unroll") for (int r = 0; r < 4; ++r)                                    \
                _Pragma("unroll") for (int cc = 0; cc < 4; ++cc)                             \
                    acc[r][cc] = __builtin_amdgcn_mfma_f32_16x16x32_bf16(af[r], bfr[cc],     \
                                                                         acc[r][cc], 0, 0, 0); \
        }                                                                                    \
    }

    uint4 pA0, pA1, pA2, pA3, pB0, pB1, pB2, pB3;
    uint4 qA0, qA1, qA2, qA3, qB0, qB1, qB2, qB3;
    QG_LOAD(0, pA0, pA1, pA2, pA3, pB0, pB1, pB2, pB3)
    QG_LOAD(1, qA0, qA1, qA2, qA3, qB0, qB1, qB2, qB3)
    QG_STORE(0, pA0, pA1, pA2, pA3, pB0, pB1, pB2, pB3)
    __syncthreads();
    for (int ks = 0; ks < 6; ks += 2) {
        QG_LOAD(ks + 2, pA0, pA1, pA2, pA3, pB0, pB1, pB2, pB3)
        QG_COMPUTE(0)
        QG_STORE(1, qA0, qA1, qA2, qA3, qB0, qB1, qB2, qB3)
        __syncthreads();
        QG_LOAD(ks + 3, qA0, qA1, qA2, qA3, qB0, qB1, qB2, qB3)
        QG_COMPUTE(1)
        QG_STORE(0, pA0, pA1, pA2, pA3, pB0, pB1, pB2, pB3)
        __syncthreads();
    }
    QG_COMPUTE(0)
    QG_STORE(1, qA0, qA1, qA2, qA3, qB0, qB1, qB2, qB3)
    __syncthreads();
    QG_COMPUTE(1)

    float bv[4];
#pragma unroll
    for (int c = 0; c < 4; ++c) bv[c] = bias[n0 + wc * 64 + c * 16 + ln];
#pragma unroll
    for (int r = 0; r < 4; ++r)
#pragma unroll
        for (int c = 0; c < 4; ++c)
#pragma unroll
            for (int q = 0; q < 4; ++q) {
                int row = m0 + wr * 64 + r * 16 + lg * 4 + q;
                int col = n0 + wc * 64 + c * 16 + ln;
                Qb[(size_t)row * 512 + col] = f2bf(acc[r][c][q] + bv[c]);
            }
}

// ---------------- sgemm: P = exp(mask(Q X^T)) -> packed tiles, padded LDS-bounce store --------
__global__ __launch_bounds__(256, 3) void sgemm_kernel(const ushort* __restrict__ Qb,
                                                       const ushort* __restrict__ Xb,
                                                       ushort* __restrict__ Pb,
                                                       int g0, int G) {
    __shared__ ushort SMEM[20480];     // 40KB: K-loop = At[2]|Bt[2] (pitch 40); epilogue = P tile
#define SG_AT(C) (SMEM + (C) * 5120)
#define SG_BT(C) (SMEM + 10240 + (C) * 5120)
    int t  = threadIdx.x;
    int bL = blockIdx.x;
    int b  = g0 + bL;
    int c  = blockIdx.y;               // 0..135 (uniform work)
    int it = 0, base = 0;
    for (;;) { if (c < base + it + 1) break; base += it + 1; ++it; }
    int jt = c - base;

    int m0 = it << 7, n0 = jt << 7;
    int w  = t >> 6, l = t & 63, ln = l & 15, lg = l >> 4;
    int wr = w >> 1, wc = w & 1;

    const ushort* Arow = Qb + (size_t)(b * SEQ + m0) * 512;
    const ushort* Brow = Xb + (size_t)(b * SEQ + n0) * 512;

    f32x4 acc[4][4] = {};
    int srow = t >> 2;
    int sc8  = (t & 3) * 8;

#define SG_LOAD(KS, A0, A1, B0, B1)                                                \
    A0 = *(const uint4*)(Arow + (size_t)srow * 512 + (KS) * 32 + sc8);             \
    A1 = *(const uint4*)(Arow + (size_t)(64 + srow) * 512 + (KS) * 32 + sc8);      \
    B0 = *(const uint4*)(Brow + (size_t)srow * 512 + (KS) * 32 + sc8);             \
    B1 = *(const uint4*)(Brow + (size_t)(64 + srow) * 512 + (KS) * 32 + sc8);

#define SG_STORE(CUR, A0, A1, B0, B1)                       \
    {                                                       \
        *(uint4*)&SG_AT(CUR)[srow * 40 + sc8]        = A0;  \
        *(uint4*)&SG_AT(CUR)[(64 + srow) * 40 + sc8] = A1;  \
        *(uint4*)&SG_BT(CUR)[srow * 40 + sc8]        = B0;  \
        *(uint4*)&SG_BT(CUR)[(64 + srow) * 40 + sc8] = B1;  \
    }

#define SG_COMPUTE(CUR)                                                                    \
    {                                                                                      \
        bf16x8 af[4], bfr[4];                                                              \
        _Pragma("unroll") for (int r = 0; r < 4; ++r)                                      \
            af[r] = *(const bf16x8*)&SG_AT(CUR)[(wr * 64 + r * 16 + ln) * 40 + lg * 8];    \
        _Pragma("unroll") for (int cc = 0; cc < 4; ++cc)                                   \
            bfr[cc] = *(const bf16x8*)&SG_BT(CUR)[(wc * 64 + cc * 16 + ln) * 40 + lg * 8]; \
        _Pragma("unroll") for (int r = 0; r < 4; ++r)                                      \
            _Pragma("unroll") for (int cc = 0; cc < 4; ++cc)                               \
                acc[r][cc] = __builtin_amdgcn_mfma_f32_16x16x32_bf16(af[r], bfr[cc],       \
                                                                     acc[r][cc], 0, 0, 0); \
    }

    uint4 pA0, pA1, pB0, pB1, qA0, qA1, qB0, qB1;
    SG_LOAD(0, pA0, pA1, pB0, pB1)
    SG_LOAD(1, qA0, qA1, qB0, qB1)
    SG_STORE(0, pA0, pA1, pB0, pB1)
    __syncthreads();
    for (int ks = 0; ks < 14; ks += 2) {
        SG_LOAD(ks + 2, pA0, pA1, pB0, pB1)
        SG_COMPUTE(0)
        SG_STORE(1, qA0, qA1, qB0, qB1)
        __syncthreads();
        SG_LOAD(ks + 3, qA0, qA1, qB0, qB1)
        SG_COMPUTE(1)
        SG_STORE(0, pA0, pA1, pB0, pB1)
        __syncthreads();
    }
    SG_COMPUTE(0)
    SG_STORE(1, qA0, qA1, qB0, qB1)
    __syncthreads();
    SG_COMPUTE(1)
    __syncthreads();                   // LDS free -> reuse as P-tile bounce (pitch 136)

    // mask + exp -> LDS P tile [128][136] bf16 (pad: lg-groups land 16 banks apart -> 2-way)
#pragma unroll
    for (int r = 0; r < 4; ++r)
#pragma unroll
        for (int q = 0; q < 4; ++q) {
            int prow = wr * 64 + r * 16 + lg * 4 + q;      // local i
            int grow = m0 + prow;                          // in-batch i
#pragma unroll
            for (int cc = 0; cc < 4; ++cc) {
                int pcol = wc * 64 + cc * 16 + ln;
                int col  = n0 + pcol;                      // in-batch j
                float ex = (col < grow) ? __expf(acc[r][cc][q]) : 0.f;
                SMEM[prow * 136 + pcol] = f2bf(ex);
            }
        }
    __syncthreads();

    // coalesced copy-out from pitch-136 tile: thread t -> row = k2*16 + (t>>4), col = (t&15)*8
    ushort* ptile = Pb + ((size_t)c * G + bL) * 16384;
    int crow = t >> 4;                 // 0..15
    int ccol = (t & 15) * 8;           // 0..120
#pragma unroll
    for (int k2 = 0; k2 < 8; ++k2) {
        int row = k2 * 16 + crow;
        *(uint4*)(ptile + row * 128 + ccol) = *(const uint4*)(SMEM + row * 136 + ccol);
    }
}

// ---------------- pvgemm: out = (P @ X)/(den+1e-10), BK=64, swizzled pitch-64, 3 blk/CU -------
// Grid (G, 128): it = 15-(y>>3) heavy-first, ht = y&7 -> 64-col slice. Nontemporal out stores.
__global__ __launch_bounds__(256, 3) void pvgemm_kernel(const ushort* __restrict__ Pb,
                                                        const ushort* __restrict__ Xt,
                                                        float* __restrict__ out,
                                                        int g0, int G) {
    __shared__ ushort Ap[2][128 * 64];
    __shared__ ushort Bp[2][64 * 64];
    __shared__ float  dden[128];
    int t  = threadIdx.x;
    int bL = blockIdx.x;
    int b  = g0 + bL;
    int y  = blockIdx.y;
    int it = 15 - (y >> 3);
    int ht = y & 7;                    // 0..7
    int n0 = ht << 6;
    int m0 = it << 7;
    int Tit = (it * (it + 1)) >> 1;
    int nks = (it + 1) * 2;            // BK=64 steps

    int w = t >> 6, l = t & 63, ln = l & 15, lg = l >> 4;
    int wr = w >> 1, wc = w & 1;       // wave tile: rows wr*64.., cols wc*32..
    int arow = t >> 1;                 // A staging: 0..127
    int acb  = (t & 1) * 4;            // A chunk base (16B chunks)
    int brow = t >> 2;                 // B staging: 0..63 (h index)
    int bcb  = (t & 3) * 2;            // B chunk base

    // swizzled staging chunk offsets (shorts)
    int aswz0 = ((acb + 0) ^ (arow & 7)) * 8;
    int aswz1 = ((acb + 1) ^ (arow & 7)) * 8;
    int aswz2 = ((acb + 2) ^ (arow & 7)) * 8;
    int aswz3 = ((acb + 3) ^ (arow & 7)) * 8;
    int bswz0 = ((bcb + 0) ^ (brow & 7)) * 8;
    int bswz1 = ((bcb + 1) ^ (brow & 7)) * 8;
    // swizzled read chunk offsets: chunk = kk*4 + lg, row&7 = ln&7
    int rsw0 = ((0 * 4 + lg) ^ (ln & 7)) * 8;   // kk=0
    int rsw1 = ((1 * 4 + lg) ^ (ln & 7)) * 8;   // kk=1

    const ushort* BrowX = Xt + ((size_t)b * DIM + n0) * SEQ;

    bf16x8 vones;
#pragma unroll
    for (int e = 0; e < 8; ++e) vones[e] = (__bf16)1.0f;

// step S covers K cols S*64..S*64+63; P tile = Tit + (S>>1), col half (S&1)*64
#define PV_LOAD(S, A0, A1, A2, A3, B0, B1)                                              \
    {                                                                                   \
        const ushort* pt_ = Pb + ((size_t)(Tit + ((S) >> 1)) * G + bL) * 16384          \
                            + ((S) & 1) * 64 + (size_t)arow * 128 + acb * 8;            \
        A0 = *(const uint4*)(pt_ + 0);  A1 = *(const uint4*)(pt_ + 8);                  \
        A2 = *(const uint4*)(pt_ + 16); A3 = *(const uint4*)(pt_ + 24);                 \
        const ushort* pb_ = BrowX + (size_t)brow * 2048 + (S) * 64 + bcb * 8;           \
        B0 = *(const uint4*)(pb_ + 0);  B1 = *(const uint4*)(pb_ + 8);                  \
    }
#define PV_ST(CUR, A0, A1, A2, A3, B0, B1)                       \
    {                                                            \
        ushort* la_ = &Ap[CUR][arow * 64];                       \
        *(uint4*)(la_ + aswz0) = A0;  *(uint4*)(la_ + aswz1) = A1; \
        *(uint4*)(la_ + aswz2) = A2;  *(uint4*)(la_ + aswz3) = A3; \
        ushort* lb_ = &Bp[CUR][brow * 64];                       \
        *(uint4*)(lb_ + bswz0) = B0;  *(uint4*)(lb_ + bswz1) = B1; \
    }
// PV compute over 2 k-chunks; den rides MFMA pipe (rule-#20-safe literal indices)
#define PV_COMPUTE(CUR)                                                                     \
    {                                                                                       \
        {                                                                                   \
            bf16x8 af[4], bfr[2];                                                           \
            _Pragma("unroll") for (int r = 0; r < 4; ++r)                                   \
                af[r] = *(const bf16x8*)&Ap[CUR][(wr * 64 + r * 16 + ln) * 64 + rsw0];      \
            _Pragma("unroll") for (int cc = 0; cc < 2; ++cc)                                \
                bfr[cc] = *(const bf16x8*)&Bp[CUR][(wc * 32 + cc * 16 + ln) * 64 + rsw0];   \
            if (wc == 0) {                                                                  \
                accd0 = __builtin_amdgcn_mfma_f32_16x16x32_bf16(af[0], vones, accd0, 0, 0, 0); \
                accd1 = __builtin_amdgcn_mfma_f32_16x16x32_bf16(af[1], vones, accd1, 0, 0, 0); \
            } else {                                                                        \
                accd0 = __builtin_amdgcn_mfma_f32_16x16x32_bf16(af[2], vones, accd0, 0, 0, 0); \
                accd1 = __builtin_amdgcn_mfma_f32_16x16x32_bf16(af[3], vones, accd1, 0, 0, 0); \
            }                                                                               \
            _Pragma("unroll") for (int r = 0; r < 4; ++r)                                   \
                _Pragma("unroll") for (int cc = 0; cc < 2; ++cc)                            \
                    acc[r][cc] = __builtin_amdgcn_mfma_f32_16x16x32_bf16(af[r], bfr[cc],    \
                                                                         acc[r][cc], 0, 0, 0); \
        }                                                                                   \
        {                                                                                   \
            bf16x8 af[4], bfr[2];                                                           \
            _Pragma("unroll") for (int r = 0; r < 4; ++r)                                   \
                af[r] = *(const bf16x8*)&Ap[CUR][(wr * 64 + r * 16 + ln) * 64 + rsw1];      \
            _Pragma("unroll") for (int cc = 0; cc < 2; ++cc)                                \
                bfr[cc] = *(const bf16x8*)&Bp[CUR][(wc * 32 + cc * 16 + ln) * 64 + rsw1];   \
            if (wc == 0) {                                                                  \
                accd0 = __builtin_amdgcn_mfma_f32_16x16x32_bf16(af[0], vones, accd0, 0, 0, 0); \
                accd1 = __builtin_amdgcn_mfma_f32_16x16x32_bf16(af[1], vones, accd1, 0, 0, 0); \
            } else {                                                                        \
                accd0 = __builtin_amdgcn_mfma_f32_16x16x32_bf16(af[2], vones, accd0, 0, 0, 0); \
                accd1 = __builtin_amdgcn_mfma_f32_16x16x32_bf16(af[3], vones, accd1, 0, 0, 0); \
            }                                                                               \
            _Pragma("unroll") for (int r = 0; r < 4; ++r)                                   \
                _Pragma("unroll") for (int cc = 0; cc < 2; ++cc)                            \
                    acc[r][cc] = __builtin_amdgcn_mfma_f32_16x16x32_bf16(af[r], bfr[cc],    \
                                                                         acc[r][cc], 0, 0, 0); \
        }                                                                                   \
    }

    f32x4 acc[4][2] = {};
    f32x4 accd0 = {}, accd1 = {};

    uint4 pA0, pA1, pA2, pA3, pB0, pB1;
    uint4 qA0, qA1, qA2, qA3, qB0, qB1;
    PV_LOAD(0, pA0, pA1, pA2, pA3, pB0, pB1)
    PV_LOAD(1, qA0, qA1, qA2, qA3, qB0, qB1)
    PV_ST(0, pA0, pA1, pA2, pA3, pB0, pB1)
    __syncthreads();
    for (int ks = 0; ks < nks - 2; ks += 2) {
        PV_LOAD(ks + 2, pA0, pA1, pA2, pA3, pB0, pB1)
        PV_COMPUTE(0)
        PV_ST(1, qA0, qA1, qA2, qA3, qB0, qB1)
        __syncthreads();
        if (ks + 3 < nks) PV_LOAD(ks + 3, qA0, qA1, qA2, qA3, qB0, qB1)
        PV_COMPUTE(1)
        PV_ST(0, pA0, pA1, pA2, pA3, pB0, pB1)
        __syncthreads();
    }
    PV_COMPUTE(0)
    PV_ST(1, qA0, qA1, qA2, qA3, qB0, qB1)
    __syncthreads();
    PV_COMPUTE(1)

    // publish den: every output column of accd equals the rowsum; lane ln==0 writes.
    if (ln == 0) {
#pragma unroll
        for (int q = 0; q < 4; ++q) {
            dden[wr * 64 + (wc * 2) * 16 + lg * 4 + q]     = accd0[q];
            dden[wr * 64 + (wc * 2 + 1) * 16 + lg * 4 + q] = accd1[q];
        }
    }
    __syncthreads();

#pragma unroll
    for (int r = 0; r < 4; ++r)
#pragma unroll
        for (int q = 0; q < 4; ++q) {
            int lrow = wr * 64 + r * 16 + lg * 4 + q;
            int row  = m0 + lrow;
            float inv = 1.0f / (dden[lrow] + 1e-10f);
            size_t o = (size_t)(b * SEQ + row) * 512;
#pragma unroll
            for (int cc = 0; cc < 2; ++cc)
                __builtin_nontemporal_store(acc[r][cc][q] * inv,
                                            &out[o + n0 + wc * 32 + cc * 16 + ln]);
        }
}

extern "C" void kernel_launch(void* const* d_in, const int* in_sizes, int n_in,
                              void* d_out, int out_size, void* d_ws, size_t ws_size,
                              hipStream_t stream) {
    const float* X    = (const float*)d_in[0];
    const float* W    = (const float*)d_in[1];
    const float* bias = (const float*)d_in[2];
    float* out = (float*)d_out;

    // ws layout (bytes): Xb[16.78M] | Xt[16.78M] | Qb[16.78M] | Wb[0.52M] | Pb[G*4.46M]
    ushort* ws = (ushort*)d_ws;
    ushort* Xb = ws;
    ushort* Xt = ws + 8388608;
    ushort* Qb = ws + 16777216;
    ushort* Wb = ws + 25165824;
    ushort* Pb = (ushort*)((char*)d_ws + 50855936);

    size_t avail = (ws_size > 50855936) ? (ws_size - 50855936) : 0;
    int G = 1;
    while (G < 8 && (size_t)(G * 2) * 4456448 <= avail) G *= 2;

    prep_kernel<<<dim3(8320), dim3(256), 0, stream>>>(X, Xb, Xt, W, Wb);
    qgemm_kernel<<<dim3(512), dim3(256), 0, stream>>>(Xb, Wb, bias, Qb);
    for (int g0 = 0; g0 < BATCH; g0 += G) {
        sgemm_kernel<<<dim3(G, 136), dim3(256), 0, stream>>>(Qb, Xb, Pb, g0, G);
        pvgemm_kernel<<<dim3(G, 128), dim3(256), 0, stream>>>(Pb, Xt, out, g0, G);
    }
}